// Round 5
// baseline (917.307 us; speedup 1.0000x reference)
//
#include <hip/hip_runtime.h>
#include <math.h>

#define N_DST   32768
#define N_EDGE  524288
#define LN_EPS  1e-5f

typedef __attribute__((ext_vector_type(8))) short short8b;   // 8 bf16 (4 VGPR)
typedef __attribute__((ext_vector_type(4))) short short4b;   // 4 bf16 (8 B)
typedef __attribute__((ext_vector_type(4))) float f32x4;

static __device__ __forceinline__ unsigned short f2bf(float f) {
    unsigned u = __float_as_uint(f);
    u += 0x7fff + ((u >> 16) & 1);          // round-to-nearest-even
    return (unsigned short)(u >> 16);
}
static __device__ __forceinline__ float bf2f(unsigned short s) {
    return __uint_as_float(((unsigned)s) << 16);
}

// ---------- prep: pack V-weights into MFMA B-fragment order (bf16), fold zq ----------
// Wvp flat index: ((kc*7 + n)*64 + lane)*8 + jj ; value = wkv_w[100 + n*16+(lane&15)][kc*32 + (lane>>4)*8 + jj]
__global__ void k_prep(const float* __restrict__ wkv_w, const float* __restrict__ wq_w,
                       const float* __restrict__ wq_b, const float* __restrict__ time_b,
                       unsigned short* __restrict__ Wvp, float* __restrict__ zq) {
    int idx = blockIdx.x * 256 + threadIdx.x;
    if (idx < 35840) {
        int jj = idx & 7, l = (idx >> 3) & 63, n = (idx >> 9) % 7, kc = idx / 3584;
        int c = n * 16 + (l & 15);
        int k = kc * 32 + ((l >> 4) << 3) + jj;
        float v = (c < 100 && k < 300) ? wkv_w[(size_t)(100 + c) * 300 + k] : 0.f;
        Wvp[idx] = f2bf(v);
    } else if (idx < 35940) {
        int o = idx - 35840;
        float acc = wq_b[o];
        for (int j = 0; j < 100; ++j)
            acc += cosf(time_b[j]) * wq_w[o * 200 + 100 + j];
        zq[o] = acc;
    }
}

// ---------- A[i][j] = sum_d wq_w[h*50+d][i] * wkv_w[h*50+d][j%300]  (j = h*300+kk) ----------
// C[j]    = sum_d zq[h*50+d] * wkv_w[h*50+d][kk]
__global__ void k_precomp(const float* __restrict__ wq_w, const float* __restrict__ wkv_w,
                          const float* __restrict__ zq,
                          float* __restrict__ A, float* __restrict__ C) {
    int idx = blockIdx.x * 256 + threadIdx.x;
    if (idx < 60000) {
        int i = idx / 600, j = idx % 600;
        int h = j / 300, kk = j % 300;
        const float* __restrict__ wq = wq_w + (size_t)(h * 50) * 200 + i;
        const float* __restrict__ wk = wkv_w + (size_t)(h * 50) * 300 + kk;
        float acc = 0.f;
        #pragma unroll 10
        for (int d = 0; d < 50; ++d) acc = fmaf(wq[(size_t)d * 200], wk[(size_t)d * 300], acc);
        A[idx] = acc;
    } else if (idx < 60600) {
        int j = idx - 60000;
        int h = j / 300, kk = j % 300;
        float acc = 0.f;
        for (int d = 0; d < 50; ++d)
            acc = fmaf(zq[h * 50 + d], wkv_w[(size_t)(h * 50 + d) * 300 + kk], acc);
        C[j] = acc;
    }
}

// ---------- CSR offsets via binary search over sorted edge_dst ----------
__global__ void k_offsets(const int* __restrict__ dst, int* __restrict__ off) {
    int n = blockIdx.x * 256 + threadIdx.x;
    if (n > N_DST) return;
    int lo = 0, hi = N_EDGE;
    while (lo < hi) {
        int mid = (lo + hi) >> 1;
        if (dst[mid] < n) lo = mid + 1; else hi = mid;
    }
    off[n] = lo;
}

// ---------- QW = dst_h @ A + C : [32768 x 100] x [100 x 600] ----------
__global__ __launch_bounds__(256) void k_qw(const float* __restrict__ dst_h,
                                            const float* __restrict__ A,
                                            const float* __restrict__ C,
                                            float* __restrict__ QW) {
    __shared__ float Ds[16][100];
    int n0 = blockIdx.x * 16, t = threadIdx.x;
    for (int idx = t; idx < 1600; idx += 256)
        Ds[idx / 100][idx % 100] = dst_h[(size_t)n0 * 100 + idx];
    __syncthreads();
    for (int pass = 0; pass < 3; ++pass) {
        int c = pass * 256 + t;
        if (c >= 600) break;
        float cb = C[c];
        float acc[16];
        #pragma unroll
        for (int n = 0; n < 16; ++n) acc[n] = cb;
        for (int k = 0; k < 100; ++k) {
            float a = A[(size_t)k * 600 + c];
            #pragma unroll
            for (int n = 0; n < 16; ++n) acc[n] = fmaf(Ds[n][k], a, acc[n]);
        }
        #pragma unroll
        for (int n = 0; n < 16; ++n) QW[(size_t)(n0 + n) * 600 + c] = acc[n];
    }
}

// ---------- edge kernel: fused staging + fp32 logits + bf16 MFMA V-GEMM ----------
// 32 edges/block, 128 thr (2 waves), LDS 20 KiB -> 8 blocks/CU (16 waves, 50% occ).
// X in LDS bf16 [32][320], XOR-swizzled. B-frags per-kc in static registers.
__global__ __launch_bounds__(128, 4) void k_edge(
        const float* __restrict__ src_h, const float* __restrict__ efeat,
        const float* __restrict__ td,    const int* __restrict__ edge_dst,
        const float* __restrict__ time_w, const float* __restrict__ time_b,
        const unsigned short* __restrict__ Wvp, const float* __restrict__ wkv_b,
        const float* __restrict__ QW,
        unsigned short* __restrict__ Vb, float2* __restrict__ attn) {
    __shared__ alignas(16) char Xs[32 * 640];   // 20 KiB: bf16 [32][320], byte(row,k)=(row*640+2k)^((row&7)<<4)
    const int t = threadIdx.x;
    const int e0 = blockIdx.x * 32;
    const int lane = t & 63;

    // ---- staging + fp32 logits: 4 threads per edge ----
    {
        const int e = t >> 2, s = t & 3;
        const int eg = e0 + e;
        const int dst = edge_dst[eg];
        const float tdv = td[eg];
        const float* __restrict__ qwb = QW + (size_t)dst * 600;
        const float4* __restrict__ s4 = (const float4*)(src_h + (size_t)eg * 100);
        const float4* __restrict__ f4 = (const float4*)(efeat + (size_t)eg * 100);
        float p0 = 0.f, p1 = 0.f;
        #pragma unroll
        for (int j = 0; j < 20; ++j) {
            int q = s + 4 * j;                       // q in [0,80): k = 4q
            float4 x = make_float4(0.f, 0.f, 0.f, 0.f);
            if (q < 25) {
                x = s4[q];
            } else if (q < 50) {
                x = f4[q - 25];
            } else if (q < 75) {
                float4 tw = ((const float4*)time_w)[q - 50];
                float4 tb = ((const float4*)time_b)[q - 50];
                x.x = __cosf(fmaf(tdv, tw.x, tb.x));
                x.y = __cosf(fmaf(tdv, tw.y, tb.y));
                x.z = __cosf(fmaf(tdv, tw.z, tb.z));
                x.w = __cosf(fmaf(tdv, tw.w, tb.w));
            }
            if (q < 75) {
                float4 a0 = ((const float4*)qwb)[q];
                float4 a1 = ((const float4*)(qwb + 300))[q];
                p0 = fmaf(x.x, a0.x, fmaf(x.y, a0.y, fmaf(x.z, a0.z, fmaf(x.w, a0.w, p0))));
                p1 = fmaf(x.x, a1.x, fmaf(x.y, a1.y, fmaf(x.z, a1.z, fmaf(x.w, a1.w, p1))));
            }
            short4b pk;
            pk[0] = (short)f2bf(x.x); pk[1] = (short)f2bf(x.y);
            pk[2] = (short)f2bf(x.z); pk[3] = (short)f2bf(x.w);
            int wb = (e * 640 + q * 8) ^ ((e & 7) << 4);
            *(short4b*)(&Xs[wb]) = pk;
        }
        p0 += __shfl_xor(p0, 1); p0 += __shfl_xor(p0, 2);
        p1 += __shfl_xor(p1, 1); p1 += __shfl_xor(p1, 2);
        if (s == 0) {
            float l0 = p0 > 0.f ? p0 : 0.2f * p0;
            float l1 = p1 > 0.f ? p1 : 0.2f * p1;
            attn[eg] = make_float2(l0, l1);
        }
    }
    __syncthreads();

    // ---- MFMA V-GEMM: wave wv owns Mfrag wv (16 edges) x 7 Nfrags ----
    const int wv = t >> 6;
    const int col = lane & 15;
    const int arow = wv * 16 + col;
    const int abase = arow * 640 + ((lane >> 4) << 4);
    const int aswz = (arow & 7) << 4;
    const short8b* __restrict__ Wv8 = (const short8b*)Wvp;

    f32x4 acc[7];
    #pragma unroll
    for (int n = 0; n < 7; ++n) {
        int cl = n * 16 + col;
        float b = (cl < 100) ? wkv_b[100 + cl] : 0.f;
        acc[n] = (f32x4){b, b, b, b};
    }
    #pragma unroll
    for (int kc = 0; kc < 10; ++kc) {
        short8b a = *(const short8b*)(&Xs[(abase + kc * 64) ^ aswz]);
        short8b w[7];
        #pragma unroll
        for (int n = 0; n < 7; ++n)
            w[n] = Wv8[(kc * 7 + n) * 64 + lane];
        #pragma unroll
        for (int n = 0; n < 7; ++n)
            acc[n] = __builtin_amdgcn_mfma_f32_16x16x32_bf16(a, w[n], acc[n], 0, 0, 0);
    }
    // V writeout (bf16): C/D layout col=lane&15, row=(lane>>4)*4+r  [m89-verified]
    const int re = e0 + wv * 16 + ((lane >> 4) << 2);
    #pragma unroll
    for (int n = 0; n < 7; ++n) {
        int cl = n * 16 + col;
        if (cl < 100) {
            #pragma unroll
            for (int r = 0; r < 4; ++r)
                Vb[(size_t)(re + r) * 100 + cl] = f2bf(acc[n][r]);
        }
    }
}

// ---------- segment softmax + weighted V reduce: ONE WAVE PER NODE ----------
__global__ __launch_bounds__(256) void k_soft(const float2* __restrict__ attn,
                                              const unsigned short* __restrict__ V,
                                              const int* __restrict__ off,
                                              float* __restrict__ agg) {
    const int lane = threadIdx.x & 63;
    const int n = blockIdx.x * 4 + (threadIdx.x >> 6);
    const int r0 = off[n], cnt = off[n + 1] - r0;
    float* __restrict__ aout = agg + (size_t)n * 100;
    if (cnt <= 0) {
        aout[lane] = 0.f;
        if (lane < 36) aout[64 + lane] = 0.f;
        return;
    }
    float m0 = -1e30f, m1 = -1e30f;
    for (int i = lane; i < cnt; i += 64) {
        float2 a = attn[r0 + i];
        m0 = fmaxf(m0, a.x); m1 = fmaxf(m1, a.y);
    }
    #pragma unroll
    for (int s = 1; s < 64; s <<= 1) {
        m0 = fmaxf(m0, __shfl_xor(m0, s));
        m1 = fmaxf(m1, __shfl_xor(m1, s));
    }
    float s0 = 0.f, s1 = 0.f;
    for (int i = lane; i < cnt; i += 64) {
        float2 a = attn[r0 + i];
        s0 += __expf(a.x - m0); s1 += __expf(a.y - m1);
    }
    #pragma unroll
    for (int s = 1; s < 64; s <<= 1) { s0 += __shfl_xor(s0, s); s1 += __shfl_xor(s1, s); }
    const float inv0 = 1.f / s0, inv1 = 1.f / s1;

    float acc_a = 0.f, acc_b = 0.f;
    for (int base = 0; base < cnt; base += 64) {
        int i = base + lane;
        float e0 = 0.f, e1 = 0.f;
        if (i < cnt) {
            float2 a = attn[r0 + i];
            e0 = __expf(a.x - m0) * inv0;
            e1 = __expf(a.y - m1) * inv1;
        }
        int lim = min(64, cnt - base);
        for (int j = 0; j < lim; ++j) {
            float p0 = __shfl(e0, j), p1 = __shfl(e1, j);
            const unsigned short* __restrict__ row = V + (size_t)(r0 + base + j) * 100;
            float pa = (lane < 50) ? p0 : p1;
            acc_a = fmaf(pa, bf2f(row[lane]), acc_a);
            if (lane < 36) acc_b = fmaf(p1, bf2f(row[64 + lane]), acc_b);
        }
    }
    aout[lane] = acc_a;
    if (lane < 36) aout[64 + lane] = acc_b;
}

// ---------- out proj + relu + layernorm: 4 nodes/block, wout row reused 4x ----------
__global__ __launch_bounds__(128) void k_out(const float* __restrict__ agg,
                                             const float* __restrict__ dst_h,
                                             const float* __restrict__ wout_w,
                                             const float* __restrict__ wout_b,
                                             const float* __restrict__ ln_g,
                                             const float* __restrict__ ln_b,
                                             float* __restrict__ out) {
    __shared__ float Fs[4][200];
    __shared__ float red[4][128];
    const int n0 = blockIdx.x * 4, t = threadIdx.x;
    for (int idx = t; idx < 800; idx += 128) {
        int n = idx / 200, i = idx % 200;
        Fs[n][i] = (i < 100) ? agg[(size_t)(n0 + n) * 100 + i]
                             : dst_h[(size_t)(n0 + n) * 100 + (i - 100)];
    }
    __syncthreads();
    float v[4] = {0.f, 0.f, 0.f, 0.f};
    if (t < 100) {
        float b = wout_b[t];
        v[0] = v[1] = v[2] = v[3] = b;
        const float* __restrict__ wr = wout_w + t * 200;
        for (int i = 0; i < 200; ++i) {
            float w = wr[i];
            #pragma unroll
            for (int n = 0; n < 4; ++n) v[n] = fmaf(Fs[n][i], w, v[n]);
        }
        #pragma unroll
        for (int n = 0; n < 4; ++n) v[n] = fmaxf(v[n], 0.f);
    }
    #pragma unroll
    for (int n = 0; n < 4; ++n) red[n][t] = (t < 100) ? v[n] : 0.f;
    __syncthreads();
    for (int s = 64; s > 0; s >>= 1) {
        if (t < s) {
            #pragma unroll
            for (int n = 0; n < 4; ++n) red[n][t] += red[n][t + s];
        }
        __syncthreads();
    }
    float mu[4];
    #pragma unroll
    for (int n = 0; n < 4; ++n) mu[n] = red[n][0] * 0.01f;
    __syncthreads();
    #pragma unroll
    for (int n = 0; n < 4; ++n) {
        float dv = (t < 100) ? (v[n] - mu[n]) : 0.f;
        red[n][t] = dv * dv;
    }
    __syncthreads();
    for (int s = 64; s > 0; s >>= 1) {
        if (t < s) {
            #pragma unroll
            for (int n = 0; n < 4; ++n) red[n][t] += red[n][t + s];
        }
        __syncthreads();
    }
    if (t < 100) {
        #pragma unroll
        for (int n = 0; n < 4; ++n) {
            float var = red[n][0] * 0.01f;
            out[(size_t)(n0 + n) * 100 + t] =
                (v[n] - mu[n]) * rsqrtf(var + LN_EPS) * ln_g[t] + ln_b[t];
        }
    }
}

extern "C" void kernel_launch(void* const* d_in, const int* in_sizes, int n_in,
                              void* d_out, int out_size, void* d_ws, size_t ws_size,
                              hipStream_t stream) {
    const float* dst_h   = (const float*)d_in[0];
    const float* src_h   = (const float*)d_in[1];
    const float* efeat   = (const float*)d_in[2];
    const float* td      = (const float*)d_in[3];
    const int*   edst    = (const int*)  d_in[4];
    const float* time_w  = (const float*)d_in[5];
    const float* time_b  = (const float*)d_in[6];
    const float* wq_w    = (const float*)d_in[7];
    const float* wq_b    = (const float*)d_in[8];
    const float* wkv_w   = (const float*)d_in[9];
    const float* wkv_b   = (const float*)d_in[10];
    const float* wout_w  = (const float*)d_in[11];
    const float* wout_b  = (const float*)d_in[12];
    const float* ln_g    = (const float*)d_in[13];
    const float* ln_b    = (const float*)d_in[14];
    float* out = (float*)d_out;

    char* ws = (char*)d_ws;
    size_t off = 0;
    auto carve = [&](size_t bytes) { char* p = ws + off; off = (off + bytes + 255) & ~(size_t)255; return p; };
    float*          QW   = (float*)carve((size_t)N_DST * 600 * 4);
    float2*         attn = (float2*)carve((size_t)N_EDGE * 2 * 4);
    unsigned short* Vb   = (unsigned short*)carve((size_t)N_EDGE * 100 * 2);
    float*          agg  = (float*)carve((size_t)N_DST * 100 * 4);
    unsigned short* Wvp  = (unsigned short*)carve(35840 * 2);
    float*          zq   = (float*)carve(100 * 4);
    float*          A    = (float*)carve(60000 * 4);
    float*          C    = (float*)carve(600 * 4);
    int*            offs = (int*)carve((size_t)(N_DST + 1) * 4);

    k_prep<<<(35940 + 255) / 256, 256, 0, stream>>>(wkv_w, wq_w, wq_b, time_b, Wvp, zq);
    k_precomp<<<(60600 + 255) / 256, 256, 0, stream>>>(wq_w, wkv_w, zq, A, C);
    k_offsets<<<(N_DST + 1 + 255) / 256, 256, 0, stream>>>(edst, offs);
    k_qw<<<N_DST / 16, 256, 0, stream>>>(dst_h, A, C, QW);
    k_edge<<<N_EDGE / 32, 128, 0, stream>>>(src_h, efeat, td, edst, time_w, time_b,
                                            Wvp, wkv_b, QW, Vb, attn);
    k_soft<<<N_DST / 4, 256, 0, stream>>>(attn, Vb, offs, agg);
    k_out<<<N_DST / 4, 128, 0, stream>>>(agg, dst_h, wout_w, wout_b, ln_g, ln_b, out);
}

// Round 6
// 852.219 us; speedup vs baseline: 1.0764x; 1.0764x over previous
//
#include <hip/hip_runtime.h>
#include <math.h>

#define N_DST   32768
#define N_EDGE  524288
#define LN_EPS  1e-5f

typedef __attribute__((ext_vector_type(8))) short short8b;   // 8 bf16 (4 VGPR)
typedef __attribute__((ext_vector_type(4))) float f32x4;

static __device__ __forceinline__ unsigned short f2bf(float f) {
    unsigned u = __float_as_uint(f);
    u += 0x7fff + ((u >> 16) & 1);          // round-to-nearest-even
    return (unsigned short)(u >> 16);
}
static __device__ __forceinline__ float bf2f(unsigned short s) {
    return __uint_as_float(((unsigned)s) << 16);
}
static __device__ __forceinline__ float dot4(float4 a, float4 b, float acc) {
    return fmaf(a.x, b.x, fmaf(a.y, b.y, fmaf(a.z, b.z, fmaf(a.w, b.w, acc))));
}

// ---------- prep: pack V-weights into MFMA B-frag order over padded K' space ----------
// K' = 384: region r = k'>>7 (0=src,1=efeat,2=time), idx = k'&127, real k = r*100+idx (idx<100 else 0).
// Wvp[((kc*7+n)*64+l)*8+jj] = wkv_w[100 + n*16+(l&15)][r*100+idx], k' = kc*32+(l>>4)*8+jj
__global__ void k_prep(const float* __restrict__ wkv_w, const float* __restrict__ wq_w,
                       const float* __restrict__ wq_b, const float* __restrict__ time_b,
                       unsigned short* __restrict__ Wvp, float* __restrict__ zq) {
    int idx = blockIdx.x * 256 + threadIdx.x;
    if (idx < 43008) {
        int jj = idx & 7, l = (idx >> 3) & 63, n = (idx >> 9) % 7, kc = idx / 3584;
        int c = n * 16 + (l & 15);
        int kp = kc * 32 + ((l >> 4) << 3) + jj;
        int region = kp >> 7, ridx = kp & 127;
        float v = (c < 100 && ridx < 100)
                  ? wkv_w[(size_t)(100 + c) * 300 + region * 100 + ridx] : 0.f;
        Wvp[idx] = f2bf(v);
    } else if (idx < 43108) {
        int o = idx - 43008;
        float acc = wq_b[o];
        for (int j = 0; j < 100; ++j)
            acc += cosf(time_b[j]) * wq_w[o * 200 + 100 + j];
        zq[o] = acc;
    }
}

// ---------- A[i][j] = sum_d wq_w[h*50+d][i] * wkv_w[h*50+d][j%300]  (j = h*300+kk) ----------
__global__ void k_precomp(const float* __restrict__ wq_w, const float* __restrict__ wkv_w,
                          const float* __restrict__ zq,
                          float* __restrict__ A, float* __restrict__ C) {
    int idx = blockIdx.x * 256 + threadIdx.x;
    if (idx < 60000) {
        int i = idx / 600, j = idx % 600;
        int h = j / 300, kk = j % 300;
        const float* __restrict__ wq = wq_w + (size_t)(h * 50) * 200 + i;
        const float* __restrict__ wk = wkv_w + (size_t)(h * 50) * 300 + kk;
        float acc = 0.f;
        #pragma unroll 10
        for (int d = 0; d < 50; ++d) acc = fmaf(wq[(size_t)d * 200], wk[(size_t)d * 300], acc);
        A[idx] = acc;
    } else if (idx < 60600) {
        int j = idx - 60000;
        int h = j / 300, kk = j % 300;
        float acc = 0.f;
        for (int d = 0; d < 50; ++d)
            acc = fmaf(zq[h * 50 + d], wkv_w[(size_t)(h * 50 + d) * 300 + kk], acc);
        C[j] = acc;
    }
}

// ---------- CSR offsets via binary search over sorted edge_dst ----------
__global__ void k_offsets(const int* __restrict__ dst, int* __restrict__ off) {
    int n = blockIdx.x * 256 + threadIdx.x;
    if (n > N_DST) return;
    int lo = 0, hi = N_EDGE;
    while (lo < hi) {
        int mid = (lo + hi) >> 1;
        if (dst[mid] < n) lo = mid + 1; else hi = mid;
    }
    off[n] = lo;
}

// ---------- QW = dst_h @ A + C : [32768 x 100] x [100 x 600] ----------
__global__ __launch_bounds__(256) void k_qw(const float* __restrict__ dst_h,
                                            const float* __restrict__ A,
                                            const float* __restrict__ C,
                                            float* __restrict__ QW) {
    __shared__ float Ds[16][100];
    int n0 = blockIdx.x * 16, t = threadIdx.x;
    for (int idx = t; idx < 1600; idx += 256)
        Ds[idx / 100][idx % 100] = dst_h[(size_t)n0 * 100 + idx];
    __syncthreads();
    for (int pass = 0; pass < 3; ++pass) {
        int c = pass * 256 + t;
        if (c >= 600) break;
        float cb = C[c];
        float acc[16];
        #pragma unroll
        for (int n = 0; n < 16; ++n) acc[n] = cb;
        for (int k = 0; k < 100; ++k) {
            float a = A[(size_t)k * 600 + c];
            #pragma unroll
            for (int n = 0; n < 16; ++n) acc[n] = fmaf(Ds[n][k], a, acc[n]);
        }
        #pragma unroll
        for (int n = 0; n < 16; ++n) QW[(size_t)(n0 + n) * 600 + c] = acc[n];
    }
}

// ---------- edge kernel: LDS-free. A-frags built in registers; fp32 logits fused ----------
// Wave handles 2 groups of 16 edges. Per lane: A row = g*16+(lane&15), k-slice = (lane>>4)*8.
// Padded K' = 384 (3 regions x 128) so the region is uniform per kc (= kc>>2).
__global__ __launch_bounds__(256, 3) void k_edge(
        const float* __restrict__ src_h, const float* __restrict__ efeat,
        const float* __restrict__ td,    const int* __restrict__ edge_dst,
        const float* __restrict__ time_w, const float* __restrict__ time_b,
        const unsigned short* __restrict__ Wvp, const float* __restrict__ wkv_b,
        const float* __restrict__ QW,
        unsigned short* __restrict__ Vb, float2* __restrict__ attn) {
    const int t = threadIdx.x, lane = t & 63;
    const int g0 = blockIdx.x * 8 + (t >> 6) * 2;      // this wave: groups g0, g0+1
    const int col = lane & 15, slice = lane >> 4;
    const int r0 = g0 * 16 + col, r1 = r0 + 16;
    const int d0 = edge_dst[r0], d1 = edge_dst[r1];
    const float td0 = td[r0], td1 = td[r1];
    const float* __restrict__ qw0 = QW + (size_t)d0 * 600;
    const float* __restrict__ qw1 = QW + (size_t)d1 * 600;
    const short8b* __restrict__ Wv8 = (const short8b*)Wvp;

    f32x4 acc0[7], acc1[7];
    #pragma unroll
    for (int n = 0; n < 7; ++n) {
        int cl = n * 16 + col;
        float b = (cl < 100) ? wkv_b[100 + cl] : 0.f;
        acc0[n] = (f32x4){b, b, b, b};
        acc1[n] = (f32x4){b, b, b, b};
    }
    float p00 = 0.f, p01 = 0.f, p10 = 0.f, p11 = 0.f;

    #pragma unroll
    for (int kc = 0; kc < 12; ++kc) {
        const int idx0 = (kc & 3) * 32 + slice * 8;    // idx within region: 0..120
        const bool full = (idx0 <= 88);                // 8 valid elems
        const bool part = (idx0 == 96);                // 4 valid elems (96..99)
        float4 z4 = make_float4(0.f, 0.f, 0.f, 0.f);
        float4 xa0 = z4, xb0 = z4, xa1 = z4, xb1 = z4;
        if (kc < 8) {                                  // src (kc<4) / efeat (kc<8)
            const float* __restrict__ base = (kc < 4) ? src_h : efeat;
            const float* b0 = base + (size_t)r0 * 100 + idx0;
            const float* b1 = base + (size_t)r1 * 100 + idx0;
            if (full) {
                xa0 = *(const float4*)b0; xb0 = *(const float4*)(b0 + 4);
                xa1 = *(const float4*)b1; xb1 = *(const float4*)(b1 + 4);
            } else if (part) {
                xa0 = *(const float4*)b0; xa1 = *(const float4*)b1;
            }
        } else {                                       // time features
            if (full || part) {
                float4 tw = *(const float4*)(time_w + idx0);
                float4 tb = *(const float4*)(time_b + idx0);
                xa0.x = __cosf(fmaf(td0, tw.x, tb.x)); xa0.y = __cosf(fmaf(td0, tw.y, tb.y));
                xa0.z = __cosf(fmaf(td0, tw.z, tb.z)); xa0.w = __cosf(fmaf(td0, tw.w, tb.w));
                xa1.x = __cosf(fmaf(td1, tw.x, tb.x)); xa1.y = __cosf(fmaf(td1, tw.y, tb.y));
                xa1.z = __cosf(fmaf(td1, tw.z, tb.z)); xa1.w = __cosf(fmaf(td1, tw.w, tb.w));
                if (full) {
                    float4 tw2 = *(const float4*)(time_w + idx0 + 4);
                    float4 tb2 = *(const float4*)(time_b + idx0 + 4);
                    xb0.x = __cosf(fmaf(td0, tw2.x, tb2.x)); xb0.y = __cosf(fmaf(td0, tw2.y, tb2.y));
                    xb0.z = __cosf(fmaf(td0, tw2.z, tb2.z)); xb0.w = __cosf(fmaf(td0, tw2.w, tb2.w));
                    xb1.x = __cosf(fmaf(td1, tw2.x, tb2.x)); xb1.y = __cosf(fmaf(td1, tw2.y, tb2.y));
                    xb1.z = __cosf(fmaf(td1, tw2.z, tb2.z)); xb1.w = __cosf(fmaf(td1, tw2.w, tb2.w));
                }
            }
        }
        // fused fp32 logits: p += x . QW[dst] over this lane's k-slice
        if (full || part) {
            const int kb = (kc >> 2) * 100 + idx0;
            p00 = dot4(xa0, *(const float4*)(qw0 + kb),       p00);
            p01 = dot4(xa0, *(const float4*)(qw0 + 300 + kb), p01);
            p10 = dot4(xa1, *(const float4*)(qw1 + kb),       p10);
            p11 = dot4(xa1, *(const float4*)(qw1 + 300 + kb), p11);
            if (full) {
                p00 = dot4(xb0, *(const float4*)(qw0 + kb + 4),       p00);
                p01 = dot4(xb0, *(const float4*)(qw0 + 304 + kb),     p01);
                p10 = dot4(xb1, *(const float4*)(qw1 + kb + 4),       p10);
                p11 = dot4(xb1, *(const float4*)(qw1 + 304 + kb),     p11);
            }
        }
        // pack A fragments (bf16)
        short8b a0, a1;
        a0[0] = (short)f2bf(xa0.x); a0[1] = (short)f2bf(xa0.y);
        a0[2] = (short)f2bf(xa0.z); a0[3] = (short)f2bf(xa0.w);
        a0[4] = (short)f2bf(xb0.x); a0[5] = (short)f2bf(xb0.y);
        a0[6] = (short)f2bf(xb0.z); a0[7] = (short)f2bf(xb0.w);
        a1[0] = (short)f2bf(xa1.x); a1[1] = (short)f2bf(xa1.y);
        a1[2] = (short)f2bf(xa1.z); a1[3] = (short)f2bf(xa1.w);
        a1[4] = (short)f2bf(xb1.x); a1[5] = (short)f2bf(xb1.y);
        a1[6] = (short)f2bf(xb1.z); a1[7] = (short)f2bf(xb1.w);
        // B frags + MFMA (w transient: 1 frag live at a time)
        #pragma unroll
        for (int n = 0; n < 7; ++n) {
            short8b w = Wv8[(kc * 7 + n) * 64 + lane];
            acc0[n] = __builtin_amdgcn_mfma_f32_16x16x32_bf16(a0, w, acc0[n], 0, 0, 0);
            acc1[n] = __builtin_amdgcn_mfma_f32_16x16x32_bf16(a1, w, acc1[n], 0, 0, 0);
        }
    }
    // logit slice-reduce across the 4 k-slices, leaky, write
    p00 += __shfl_xor(p00, 16); p00 += __shfl_xor(p00, 32);
    p01 += __shfl_xor(p01, 16); p01 += __shfl_xor(p01, 32);
    p10 += __shfl_xor(p10, 16); p10 += __shfl_xor(p10, 32);
    p11 += __shfl_xor(p11, 16); p11 += __shfl_xor(p11, 32);
    if (slice == 0) {
        attn[r0] = make_float2(p00 > 0.f ? p00 : 0.2f * p00,
                               p01 > 0.f ? p01 : 0.2f * p01);
        attn[r1] = make_float2(p10 > 0.f ? p10 : 0.2f * p10,
                               p11 > 0.f ? p11 : 0.2f * p11);
    }
    // V writeout (bf16): C/D layout col=lane&15, row=(lane>>4)*4+r  [m89-verified]
    const int re0 = g0 * 16 + (slice << 2);
    #pragma unroll
    for (int n = 0; n < 7; ++n) {
        int cl = n * 16 + col;
        if (cl < 100) {
            #pragma unroll
            for (int r = 0; r < 4; ++r) {
                Vb[(size_t)(re0 + r) * 100 + cl]      = f2bf(acc0[n][r]);
                Vb[(size_t)(re0 + 16 + r) * 100 + cl] = f2bf(acc1[n][r]);
            }
        }
    }
}

// ---------- segment softmax + weighted V reduce: ONE WAVE PER NODE ----------
__global__ __launch_bounds__(256) void k_soft(const float2* __restrict__ attn,
                                              const unsigned short* __restrict__ V,
                                              const int* __restrict__ off,
                                              float* __restrict__ agg) {
    const int lane = threadIdx.x & 63;
    const int n = blockIdx.x * 4 + (threadIdx.x >> 6);
    const int r0 = off[n], cnt = off[n + 1] - r0;
    float* __restrict__ aout = agg + (size_t)n * 100;
    if (cnt <= 0) {
        aout[lane] = 0.f;
        if (lane < 36) aout[64 + lane] = 0.f;
        return;
    }
    float m0 = -1e30f, m1 = -1e30f;
    for (int i = lane; i < cnt; i += 64) {
        float2 a = attn[r0 + i];
        m0 = fmaxf(m0, a.x); m1 = fmaxf(m1, a.y);
    }
    #pragma unroll
    for (int s = 1; s < 64; s <<= 1) {
        m0 = fmaxf(m0, __shfl_xor(m0, s));
        m1 = fmaxf(m1, __shfl_xor(m1, s));
    }
    float s0 = 0.f, s1 = 0.f;
    for (int i = lane; i < cnt; i += 64) {
        float2 a = attn[r0 + i];
        s0 += __expf(a.x - m0); s1 += __expf(a.y - m1);
    }
    #pragma unroll
    for (int s = 1; s < 64; s <<= 1) { s0 += __shfl_xor(s0, s); s1 += __shfl_xor(s1, s); }
    const float inv0 = 1.f / s0, inv1 = 1.f / s1;

    float acc_a = 0.f, acc_b = 0.f;
    for (int base = 0; base < cnt; base += 64) {
        int i = base + lane;
        float e0 = 0.f, e1 = 0.f;
        if (i < cnt) {
            float2 a = attn[r0 + i];
            e0 = __expf(a.x - m0) * inv0;
            e1 = __expf(a.y - m1) * inv1;
        }
        int lim = min(64, cnt - base);
        for (int j = 0; j < lim; ++j) {
            float p0 = __shfl(e0, j), p1 = __shfl(e1, j);
            const unsigned short* __restrict__ row = V + (size_t)(r0 + base + j) * 100;
            float pa = (lane < 50) ? p0 : p1;
            acc_a = fmaf(pa, bf2f(row[lane]), acc_a);
            if (lane < 36) acc_b = fmaf(p1, bf2f(row[64 + lane]), acc_b);
        }
    }
    aout[lane] = acc_a;
    if (lane < 36) aout[64 + lane] = acc_b;
}

// ---------- out proj + relu + layernorm: 4 nodes/block, wout row reused 4x ----------
__global__ __launch_bounds__(128) void k_out(const float* __restrict__ agg,
                                             const float* __restrict__ dst_h,
                                             const float* __restrict__ wout_w,
                                             const float* __restrict__ wout_b,
                                             const float* __restrict__ ln_g,
                                             const float* __restrict__ ln_b,
                                             float* __restrict__ out) {
    __shared__ float Fs[4][200];
    __shared__ float red[4][128];
    const int n0 = blockIdx.x * 4, t = threadIdx.x;
    for (int idx = t; idx < 800; idx += 128) {
        int n = idx / 200, i = idx % 200;
        Fs[n][i] = (i < 100) ? agg[(size_t)(n0 + n) * 100 + i]
                             : dst_h[(size_t)(n0 + n) * 100 + (i - 100)];
    }
    __syncthreads();
    float v[4] = {0.f, 0.f, 0.f, 0.f};
    if (t < 100) {
        float b = wout_b[t];
        v[0] = v[1] = v[2] = v[3] = b;
        const float* __restrict__ wr = wout_w + t * 200;
        for (int i = 0; i < 200; ++i) {
            float w = wr[i];
            #pragma unroll
            for (int n = 0; n < 4; ++n) v[n] = fmaf(Fs[n][i], w, v[n]);
        }
        #pragma unroll
        for (int n = 0; n < 4; ++n) v[n] = fmaxf(v[n], 0.f);
    }
    #pragma unroll
    for (int n = 0; n < 4; ++n) red[n][t] = (t < 100) ? v[n] : 0.f;
    __syncthreads();
    for (int s = 64; s > 0; s >>= 1) {
        if (t < s) {
            #pragma unroll
            for (int n = 0; n < 4; ++n) red[n][t] += red[n][t + s];
        }
        __syncthreads();
    }
    float mu[4];
    #pragma unroll
    for (int n = 0; n < 4; ++n) mu[n] = red[n][0] * 0.01f;
    __syncthreads();
    #pragma unroll
    for (int n = 0; n < 4; ++n) {
        float dv = (t < 100) ? (v[n] - mu[n]) : 0.f;
        red[n][t] = dv * dv;
    }
    __syncthreads();
    for (int s = 64; s > 0; s >>= 1) {
        if (t < s) {
            #pragma unroll
            for (int n = 0; n < 4; ++n) red[n][t] += red[n][t + s];
        }
        __syncthreads();
    }
    if (t < 100) {
        #pragma unroll
        for (int n = 0; n < 4; ++n) {
            float var = red[n][0] * 0.01f;
            out[(size_t)(n0 + n) * 100 + t] =
                (v[n] - mu[n]) * rsqrtf(var + LN_EPS) * ln_g[t] + ln_b[t];
        }
    }
}

extern "C" void kernel_launch(void* const* d_in, const int* in_sizes, int n_in,
                              void* d_out, int out_size, void* d_ws, size_t ws_size,
                              hipStream_t stream) {
    const float* dst_h   = (const float*)d_in[0];
    const float* src_h   = (const float*)d_in[1];
    const float* efeat   = (const float*)d_in[2];
    const float* td      = (const float*)d_in[3];
    const int*   edst    = (const int*)  d_in[4];
    const float* time_w  = (const float*)d_in[5];
    const float* time_b  = (const float*)d_in[6];
    const float* wq_w    = (const float*)d_in[7];
    const float* wq_b    = (const float*)d_in[8];
    const float* wkv_w   = (const float*)d_in[9];
    const float* wkv_b   = (const float*)d_in[10];
    const float* wout_w  = (const float*)d_in[11];
    const float* wout_b  = (const float*)d_in[12];
    const float* ln_g    = (const float*)d_in[13];
    const float* ln_b    = (const float*)d_in[14];
    float* out = (float*)d_out;

    char* ws = (char*)d_ws;
    size_t off = 0;
    auto carve = [&](size_t bytes) { char* p = ws + off; off = (off + bytes + 255) & ~(size_t)255; return p; };
    float*          QW   = (float*)carve((size_t)N_DST * 600 * 4);
    float2*         attn = (float2*)carve((size_t)N_EDGE * 2 * 4);
    unsigned short* Vb   = (unsigned short*)carve((size_t)N_EDGE * 100 * 2);
    float*          agg  = (float*)carve((size_t)N_DST * 100 * 4);
    unsigned short* Wvp  = (unsigned short*)carve(43008 * 2);
    float*          zq   = (float*)carve(100 * 4);
    float*          A    = (float*)carve(60000 * 4);
    float*          C    = (float*)carve(600 * 4);
    int*            offs = (int*)carve((size_t)(N_DST + 1) * 4);

    k_prep<<<(43108 + 255) / 256, 256, 0, stream>>>(wkv_w, wq_w, wq_b, time_b, Wvp, zq);
    k_precomp<<<(60600 + 255) / 256, 256, 0, stream>>>(wq_w, wkv_w, zq, A, C);
    k_offsets<<<(N_DST + 1 + 255) / 256, 256, 0, stream>>>(edst, offs);
    k_qw<<<N_DST / 16, 256, 0, stream>>>(dst_h, A, C, QW);
    k_edge<<<N_EDGE / 128, 256, 0, stream>>>(src_h, efeat, td, edst, time_w, time_b,
                                             Wvp, wkv_b, QW, Vb, attn);
    k_soft<<<N_DST / 4, 256, 0, stream>>>(attn, Vb, offs, agg);
    k_out<<<N_DST / 4, 128, 0, stream>>>(agg, dst_h, wout_w, wout_b, ln_g, ln_b, out);
}

// Round 7
// 529.681 us; speedup vs baseline: 1.7318x; 1.6089x over previous
//
#include <hip/hip_runtime.h>
#include <math.h>

#define N_DST   32768
#define N_EDGE  524288
#define LN_EPS  1e-5f

typedef __attribute__((ext_vector_type(8))) short short8b;   // 8 bf16 (4 VGPR)
typedef __attribute__((ext_vector_type(4))) float f32x4;

static __device__ __forceinline__ unsigned short f2bf(float f) {
    unsigned u = __float_as_uint(f);
    u += 0x7fff + ((u >> 16) & 1);          // round-to-nearest-even
    return (unsigned short)(u >> 16);
}
static __device__ __forceinline__ float bf2f(unsigned short s) {
    return __uint_as_float(((unsigned)s) << 16);
}
static __device__ __forceinline__ float dot4(float4 a, float4 b, float acc) {
    return fmaf(a.x, b.x, fmaf(a.y, b.y, fmaf(a.z, b.z, fmaf(a.w, b.w, acc))));
}

// ---------- prep: pack V-weights into MFMA B-frag order over padded K' space ----------
// K' = 384: region r = k'>>7 (0=src,1=efeat,2=time), idx = k'&127, real k = r*100+idx (idx<100 else 0).
// Wvp[((kc*7+n)*64+l)*8+jj] = wkv_w[100 + n*16+(l&15)][r*100+idx], k' = kc*32+(l>>4)*8+jj
__global__ void k_prep(const float* __restrict__ wkv_w, const float* __restrict__ wq_w,
                       const float* __restrict__ wq_b, const float* __restrict__ time_b,
                       unsigned short* __restrict__ Wvp, float* __restrict__ zq) {
    int idx = blockIdx.x * 256 + threadIdx.x;
    if (idx < 43008) {
        int jj = idx & 7, l = (idx >> 3) & 63, n = (idx >> 9) % 7, kc = idx / 3584;
        int c = n * 16 + (l & 15);
        int kp = kc * 32 + ((l >> 4) << 3) + jj;
        int region = kp >> 7, ridx = kp & 127;
        float v = (c < 100 && ridx < 100)
                  ? wkv_w[(size_t)(100 + c) * 300 + region * 100 + ridx] : 0.f;
        Wvp[idx] = f2bf(v);
    } else if (idx < 43108) {
        int o = idx - 43008;
        float acc = wq_b[o];
        for (int j = 0; j < 100; ++j)
            acc += cosf(time_b[j]) * wq_w[o * 200 + 100 + j];
        zq[o] = acc;
    }
}

// ---------- A[i][j] = sum_d wq_w[h*50+d][i] * wkv_w[h*50+d][j%300]  (j = h*300+kk) ----------
__global__ void k_precomp(const float* __restrict__ wq_w, const float* __restrict__ wkv_w,
                          const float* __restrict__ zq,
                          float* __restrict__ A, float* __restrict__ C) {
    int idx = blockIdx.x * 256 + threadIdx.x;
    if (idx < 60000) {
        int i = idx / 600, j = idx % 600;
        int h = j / 300, kk = j % 300;
        const float* __restrict__ wq = wq_w + (size_t)(h * 50) * 200 + i;
        const float* __restrict__ wk = wkv_w + (size_t)(h * 50) * 300 + kk;
        float acc = 0.f;
        #pragma unroll 10
        for (int d = 0; d < 50; ++d) acc = fmaf(wq[(size_t)d * 200], wk[(size_t)d * 300], acc);
        A[idx] = acc;
    } else if (idx < 60600) {
        int j = idx - 60000;
        int h = j / 300, kk = j % 300;
        float acc = 0.f;
        for (int d = 0; d < 50; ++d)
            acc = fmaf(zq[h * 50 + d], wkv_w[(size_t)(h * 50 + d) * 300 + kk], acc);
        C[j] = acc;
    }
}

// ---------- CSR offsets via binary search over sorted edge_dst ----------
__global__ void k_offsets(const int* __restrict__ dst, int* __restrict__ off) {
    int n = blockIdx.x * 256 + threadIdx.x;
    if (n > N_DST) return;
    int lo = 0, hi = N_EDGE;
    while (lo < hi) {
        int mid = (lo + hi) >> 1;
        if (dst[mid] < n) lo = mid + 1; else hi = mid;
    }
    off[n] = lo;
}

// ---------- QW = dst_h @ A + C : [32768 x 100] x [100 x 600] ----------
__global__ __launch_bounds__(256) void k_qw(const float* __restrict__ dst_h,
                                            const float* __restrict__ A,
                                            const float* __restrict__ C,
                                            float* __restrict__ QW) {
    __shared__ float Ds[16][100];
    int n0 = blockIdx.x * 16, t = threadIdx.x;
    for (int idx = t; idx < 1600; idx += 256)
        Ds[idx / 100][idx % 100] = dst_h[(size_t)n0 * 100 + idx];
    __syncthreads();
    for (int pass = 0; pass < 3; ++pass) {
        int c = pass * 256 + t;
        if (c >= 600) break;
        float cb = C[c];
        float acc[16];
        #pragma unroll
        for (int n = 0; n < 16; ++n) acc[n] = cb;
        for (int k = 0; k < 100; ++k) {
            float a = A[(size_t)k * 600 + c];
            #pragma unroll
            for (int n = 0; n < 16; ++n) acc[n] = fmaf(Ds[n][k], a, acc[n]);
        }
        #pragma unroll
        for (int n = 0; n < 16; ++n) QW[(size_t)(n0 + n) * 600 + c] = acc[n];
    }
}

// ---------- edge kernel: LDS-free, G=1 (16 edges/wave), no spill by design ----------
// Per lane: A row = g*16+(lane&15), k-slice = (lane>>4)*8. K' = 384 (3 regions x 128).
// acc[7]=28 VGPR + staging ~20 + transients: fits the 128-cap of (256,2) WITHOUT spill.
__global__ __launch_bounds__(256, 2) void k_edge(
        const float* __restrict__ src_h, const float* __restrict__ efeat,
        const float* __restrict__ td,    const int* __restrict__ edge_dst,
        const float* __restrict__ time_w, const float* __restrict__ time_b,
        const unsigned short* __restrict__ Wvp, const float* __restrict__ wkv_b,
        const float* __restrict__ QW,
        unsigned short* __restrict__ Vb, float2* __restrict__ attn) {
    const int t = threadIdx.x, lane = t & 63;
    const int g = blockIdx.x * 4 + (t >> 6);           // this wave: group g (16 edges)
    const int col = lane & 15, slice = lane >> 4;
    const int r0 = g * 16 + col;
    const int d0 = edge_dst[r0];
    const float td0 = td[r0];
    const float* __restrict__ qw0 = QW + (size_t)d0 * 600;
    const short8b* __restrict__ Wv8 = (const short8b*)Wvp;

    f32x4 acc0[7];
    #pragma unroll
    for (int n = 0; n < 7; ++n) {
        int cl = n * 16 + col;
        float b = (cl < 100) ? wkv_b[100 + cl] : 0.f;
        acc0[n] = (f32x4){b, b, b, b};
    }
    float p00 = 0.f, p01 = 0.f;

    #pragma unroll
    for (int kc = 0; kc < 12; ++kc) {
        const int idx0 = (kc & 3) * 32 + slice * 8;    // idx within region: 0..120
        const bool full = (idx0 <= 88);                // 8 valid elems
        const bool part = (idx0 == 96);                // 4 valid elems (96..99)
        float4 z4 = make_float4(0.f, 0.f, 0.f, 0.f);
        float4 xa0 = z4, xb0 = z4;
        if (kc < 8) {                                  // src (kc<4) / efeat (kc<8)
            const float* __restrict__ base = (kc < 4) ? src_h : efeat;
            const float* b0 = base + (size_t)r0 * 100 + idx0;
            if (full) {
                xa0 = *(const float4*)b0; xb0 = *(const float4*)(b0 + 4);
            } else if (part) {
                xa0 = *(const float4*)b0;
            }
        } else {                                       // time features
            if (full || part) {
                float4 tw = *(const float4*)(time_w + idx0);
                float4 tb = *(const float4*)(time_b + idx0);
                xa0.x = __cosf(fmaf(td0, tw.x, tb.x)); xa0.y = __cosf(fmaf(td0, tw.y, tb.y));
                xa0.z = __cosf(fmaf(td0, tw.z, tb.z)); xa0.w = __cosf(fmaf(td0, tw.w, tb.w));
                if (full) {
                    float4 tw2 = *(const float4*)(time_w + idx0 + 4);
                    float4 tb2 = *(const float4*)(time_b + idx0 + 4);
                    xb0.x = __cosf(fmaf(td0, tw2.x, tb2.x)); xb0.y = __cosf(fmaf(td0, tw2.y, tb2.y));
                    xb0.z = __cosf(fmaf(td0, tw2.z, tb2.z)); xb0.w = __cosf(fmaf(td0, tw2.w, tb2.w));
                }
            }
        }
        // fused fp32 logits: p += x . QW[dst] over this lane's k-slice
        if (full || part) {
            const int kb = (kc >> 2) * 100 + idx0;
            p00 = dot4(xa0, *(const float4*)(qw0 + kb),       p00);
            p01 = dot4(xa0, *(const float4*)(qw0 + 300 + kb), p01);
            if (full) {
                p00 = dot4(xb0, *(const float4*)(qw0 + kb + 4),   p00);
                p01 = dot4(xb0, *(const float4*)(qw0 + 304 + kb), p01);
            }
        }
        // pack A fragment (bf16)
        short8b a0;
        a0[0] = (short)f2bf(xa0.x); a0[1] = (short)f2bf(xa0.y);
        a0[2] = (short)f2bf(xa0.z); a0[3] = (short)f2bf(xa0.w);
        a0[4] = (short)f2bf(xb0.x); a0[5] = (short)f2bf(xb0.y);
        a0[6] = (short)f2bf(xb0.z); a0[7] = (short)f2bf(xb0.w);
        // B frags + MFMA (w transient: 1 frag live at a time)
        #pragma unroll
        for (int n = 0; n < 7; ++n) {
            short8b w = Wv8[(kc * 7 + n) * 64 + lane];
            acc0[n] = __builtin_amdgcn_mfma_f32_16x16x32_bf16(a0, w, acc0[n], 0, 0, 0);
        }
    }
    // logit slice-reduce across the 4 k-slices, leaky, write
    p00 += __shfl_xor(p00, 16); p00 += __shfl_xor(p00, 32);
    p01 += __shfl_xor(p01, 16); p01 += __shfl_xor(p01, 32);
    if (slice == 0) {
        attn[r0] = make_float2(p00 > 0.f ? p00 : 0.2f * p00,
                               p01 > 0.f ? p01 : 0.2f * p01);
    }
    // V writeout (bf16): C/D layout col=lane&15, row=(lane>>4)*4+r  [m89-verified]
    const int re0 = g * 16 + (slice << 2);
    #pragma unroll
    for (int n = 0; n < 7; ++n) {
        int cl = n * 16 + col;
        if (cl < 100) {
            #pragma unroll
            for (int r = 0; r < 4; ++r)
                Vb[(size_t)(re0 + r) * 100 + cl] = f2bf(acc0[n][r]);
        }
    }
}

// ---------- segment softmax + weighted V reduce: ONE WAVE PER NODE ----------
__global__ __launch_bounds__(256) void k_soft(const float2* __restrict__ attn,
                                              const unsigned short* __restrict__ V,
                                              const int* __restrict__ off,
                                              float* __restrict__ agg) {
    const int lane = threadIdx.x & 63;
    const int n = blockIdx.x * 4 + (threadIdx.x >> 6);
    const int r0 = off[n], cnt = off[n + 1] - r0;
    float* __restrict__ aout = agg + (size_t)n * 100;
    if (cnt <= 0) {
        aout[lane] = 0.f;
        if (lane < 36) aout[64 + lane] = 0.f;
        return;
    }
    float m0 = -1e30f, m1 = -1e30f;
    for (int i = lane; i < cnt; i += 64) {
        float2 a = attn[r0 + i];
        m0 = fmaxf(m0, a.x); m1 = fmaxf(m1, a.y);
    }
    #pragma unroll
    for (int s = 1; s < 64; s <<= 1) {
        m0 = fmaxf(m0, __shfl_xor(m0, s));
        m1 = fmaxf(m1, __shfl_xor(m1, s));
    }
    float s0 = 0.f, s1 = 0.f;
    for (int i = lane; i < cnt; i += 64) {
        float2 a = attn[r0 + i];
        s0 += __expf(a.x - m0); s1 += __expf(a.y - m1);
    }
    #pragma unroll
    for (int s = 1; s < 64; s <<= 1) { s0 += __shfl_xor(s0, s); s1 += __shfl_xor(s1, s); }
    const float inv0 = 1.f / s0, inv1 = 1.f / s1;

    float acc_a = 0.f, acc_b = 0.f;
    for (int base = 0; base < cnt; base += 64) {
        int i = base + lane;
        float e0 = 0.f, e1 = 0.f;
        if (i < cnt) {
            float2 a = attn[r0 + i];
            e0 = __expf(a.x - m0) * inv0;
            e1 = __expf(a.y - m1) * inv1;
        }
        int lim = min(64, cnt - base);
        for (int j = 0; j < lim; ++j) {
            float p0 = __shfl(e0, j), p1 = __shfl(e1, j);
            const unsigned short* __restrict__ row = V + (size_t)(r0 + base + j) * 100;
            float pa = (lane < 50) ? p0 : p1;
            acc_a = fmaf(pa, bf2f(row[lane]), acc_a);
            if (lane < 36) acc_b = fmaf(p1, bf2f(row[64 + lane]), acc_b);
        }
    }
    aout[lane] = acc_a;
    if (lane < 36) aout[64 + lane] = acc_b;
}

// ---------- out proj + relu + layernorm: 4 nodes/block, wout row reused 4x ----------
__global__ __launch_bounds__(128) void k_out(const float* __restrict__ agg,
                                             const float* __restrict__ dst_h,
                                             const float* __restrict__ wout_w,
                                             const float* __restrict__ wout_b,
                                             const float* __restrict__ ln_g,
                                             const float* __restrict__ ln_b,
                                             float* __restrict__ out) {
    __shared__ float Fs[4][200];
    __shared__ float red[4][128];
    const int n0 = blockIdx.x * 4, t = threadIdx.x;
    for (int idx = t; idx < 800; idx += 128) {
        int n = idx / 200, i = idx % 200;
        Fs[n][i] = (i < 100) ? agg[(size_t)(n0 + n) * 100 + i]
                             : dst_h[(size_t)(n0 + n) * 100 + (i - 100)];
    }
    __syncthreads();
    float v[4] = {0.f, 0.f, 0.f, 0.f};
    if (t < 100) {
        float b = wout_b[t];
        v[0] = v[1] = v[2] = v[3] = b;
        const float* __restrict__ wr = wout_w + t * 200;
        for (int i = 0; i < 200; ++i) {
            float w = wr[i];
            #pragma unroll
            for (int n = 0; n < 4; ++n) v[n] = fmaf(Fs[n][i], w, v[n]);
        }
        #pragma unroll
        for (int n = 0; n < 4; ++n) v[n] = fmaxf(v[n], 0.f);
    }
    #pragma unroll
    for (int n = 0; n < 4; ++n) red[n][t] = (t < 100) ? v[n] : 0.f;
    __syncthreads();
    for (int s = 64; s > 0; s >>= 1) {
        if (t < s) {
            #pragma unroll
            for (int n = 0; n < 4; ++n) red[n][t] += red[n][t + s];
        }
        __syncthreads();
    }
    float mu[4];
    #pragma unroll
    for (int n = 0; n < 4; ++n) mu[n] = red[n][0] * 0.01f;
    __syncthreads();
    #pragma unroll
    for (int n = 0; n < 4; ++n) {
        float dv = (t < 100) ? (v[n] - mu[n]) : 0.f;
        red[n][t] = dv * dv;
    }
    __syncthreads();
    for (int s = 64; s > 0; s >>= 1) {
        if (t < s) {
            #pragma unroll
            for (int n = 0; n < 4; ++n) red[n][t] += red[n][t + s];
        }
        __syncthreads();
    }
    if (t < 100) {
        #pragma unroll
        for (int n = 0; n < 4; ++n) {
            float var = red[n][0] * 0.01f;
            out[(size_t)(n0 + n) * 100 + t] =
                (v[n] - mu[n]) * rsqrtf(var + LN_EPS) * ln_g[t] + ln_b[t];
        }
    }
}

extern "C" void kernel_launch(void* const* d_in, const int* in_sizes, int n_in,
                              void* d_out, int out_size, void* d_ws, size_t ws_size,
                              hipStream_t stream) {
    const float* dst_h   = (const float*)d_in[0];
    const float* src_h   = (const float*)d_in[1];
    const float* efeat   = (const float*)d_in[2];
    const float* td      = (const float*)d_in[3];
    const int*   edst    = (const int*)  d_in[4];
    const float* time_w  = (const float*)d_in[5];
    const float* time_b  = (const float*)d_in[6];
    const float* wq_w    = (const float*)d_in[7];
    const float* wq_b    = (const float*)d_in[8];
    const float* wkv_w   = (const float*)d_in[9];
    const float* wkv_b   = (const float*)d_in[10];
    const float* wout_w  = (const float*)d_in[11];
    const float* wout_b  = (const float*)d_in[12];
    const float* ln_g    = (const float*)d_in[13];
    const float* ln_b    = (const float*)d_in[14];
    float* out = (float*)d_out;

    char* ws = (char*)d_ws;
    size_t off = 0;
    auto carve = [&](size_t bytes) { char* p = ws + off; off = (off + bytes + 255) & ~(size_t)255; return p; };
    float*          QW   = (float*)carve((size_t)N_DST * 600 * 4);
    float2*         attn = (float2*)carve((size_t)N_EDGE * 2 * 4);
    unsigned short* Vb   = (unsigned short*)carve((size_t)N_EDGE * 100 * 2);
    float*          agg  = (float*)carve((size_t)N_DST * 100 * 4);
    unsigned short* Wvp  = (unsigned short*)carve(43008 * 2);
    float*          zq   = (float*)carve(100 * 4);
    float*          A    = (float*)carve(60000 * 4);
    float*          C    = (float*)carve(600 * 4);
    int*            offs = (int*)carve((size_t)(N_DST + 1) * 4);

    k_prep<<<(43108 + 255) / 256, 256, 0, stream>>>(wkv_w, wq_w, wq_b, time_b, Wvp, zq);
    k_precomp<<<(60600 + 255) / 256, 256, 0, stream>>>(wq_w, wkv_w, zq, A, C);
    k_offsets<<<(N_DST + 1 + 255) / 256, 256, 0, stream>>>(edst, offs);
    k_qw<<<N_DST / 16, 256, 0, stream>>>(dst_h, A, C, QW);
    k_edge<<<N_EDGE / 64, 256, 0, stream>>>(src_h, efeat, td, edst, time_w, time_b,
                                            Wvp, wkv_b, QW, Vb, attn);
    k_soft<<<N_DST / 4, 256, 0, stream>>>(attn, Vb, offs, agg);
    k_out<<<N_DST / 4, 128, 0, stream>>>(agg, dst_h, wout_w, wout_b, ln_g, ln_b, out);
}

// Round 8
// 514.878 us; speedup vs baseline: 1.7816x; 1.0287x over previous
//
#include <hip/hip_runtime.h>
#include <math.h>

#define N_DST   32768
#define N_EDGE  524288
#define LN_EPS  1e-5f

typedef __attribute__((ext_vector_type(8))) short short8b;   // 8 bf16 (4 VGPR)
typedef __attribute__((ext_vector_type(4))) float f32x4;

static __device__ __forceinline__ unsigned short f2bf(float f) {
    unsigned u = __float_as_uint(f);
    u += 0x7fff + ((u >> 16) & 1);          // round-to-nearest-even
    return (unsigned short)(u >> 16);
}
static __device__ __forceinline__ float bf2f(unsigned short s) {
    return __uint_as_float(((unsigned)s) << 16);
}
static __device__ __forceinline__ float dot4(float4 a, float4 b, float acc) {
    return fmaf(a.x, b.x, fmaf(a.y, b.y, fmaf(a.z, b.z, fmaf(a.w, b.w, acc))));
}

// ---------- prep: Wvp B-frag pack (padded K'=384), zq fold, wout transpose ----------
__global__ void k_prep(const float* __restrict__ wkv_w, const float* __restrict__ wq_w,
                       const float* __restrict__ wq_b, const float* __restrict__ time_b,
                       const float* __restrict__ wout_w,
                       unsigned short* __restrict__ Wvp, float* __restrict__ zq,
                       float* __restrict__ wout_t) {
    int idx = blockIdx.x * 256 + threadIdx.x;
    if (idx < 43008) {
        int jj = idx & 7, l = (idx >> 3) & 63, n = (idx >> 9) % 7, kc = idx / 3584;
        int c = n * 16 + (l & 15);
        int kp = kc * 32 + ((l >> 4) << 3) + jj;
        int region = kp >> 7, ridx = kp & 127;
        float v = (c < 100 && ridx < 100)
                  ? wkv_w[(size_t)(100 + c) * 300 + region * 100 + ridx] : 0.f;
        Wvp[idx] = f2bf(v);
    } else if (idx < 43108) {
        int o = idx - 43008;
        float acc = wq_b[o];
        for (int j = 0; j < 100; ++j)
            acc += cosf(time_b[j]) * wq_w[o * 200 + 100 + j];
        zq[o] = acc;
    } else if (idx < 63108) {
        int r = idx - 43108;                     // wout_t[i][o] = wout_w[o][i]
        wout_t[r] = wout_w[(size_t)(r % 100) * 200 + r / 100];
    }
}

// ---------- A[i][j] = sum_d wq_w[h*50+d][i] * wkv_w[h*50+d][j%300]  (j = h*300+kk) ----------
__global__ void k_precomp(const float* __restrict__ wq_w, const float* __restrict__ wkv_w,
                          const float* __restrict__ zq,
                          float* __restrict__ A, float* __restrict__ C) {
    int idx = blockIdx.x * 256 + threadIdx.x;
    if (idx < 60000) {
        int i = idx / 600, j = idx % 600;
        int h = j / 300, kk = j % 300;
        const float* __restrict__ wq = wq_w + (size_t)(h * 50) * 200 + i;
        const float* __restrict__ wk = wkv_w + (size_t)(h * 50) * 300 + kk;
        float acc = 0.f;
        #pragma unroll 10
        for (int d = 0; d < 50; ++d) acc = fmaf(wq[(size_t)d * 200], wk[(size_t)d * 300], acc);
        A[idx] = acc;
    } else if (idx < 60600) {
        int j = idx - 60000;
        int h = j / 300, kk = j % 300;
        float acc = 0.f;
        for (int d = 0; d < 50; ++d)
            acc = fmaf(zq[h * 50 + d], wkv_w[(size_t)(h * 50 + d) * 300 + kk], acc);
        C[j] = acc;
    }
}

// ---------- CSR offsets via binary search over sorted edge_dst ----------
__global__ void k_offsets(const int* __restrict__ dst, int* __restrict__ off) {
    int n = blockIdx.x * 256 + threadIdx.x;
    if (n > N_DST) return;
    int lo = 0, hi = N_EDGE;
    while (lo < hi) {
        int mid = (lo + hi) >> 1;
        if (dst[mid] < n) lo = mid + 1; else hi = mid;
    }
    off[n] = lo;
}

// ---------- QW = dst_h @ A + C : [32768 x 100] x [100 x 600] ----------
__global__ __launch_bounds__(256) void k_qw(const float* __restrict__ dst_h,
                                            const float* __restrict__ A,
                                            const float* __restrict__ C,
                                            float* __restrict__ QW) {
    __shared__ float Ds[16][100];
    int n0 = blockIdx.x * 16, t = threadIdx.x;
    for (int idx = t; idx < 1600; idx += 256)
        Ds[idx / 100][idx % 100] = dst_h[(size_t)n0 * 100 + idx];
    __syncthreads();
    for (int pass = 0; pass < 3; ++pass) {
        int c = pass * 256 + t;
        if (c >= 600) break;
        float cb = C[c];
        float acc[16];
        #pragma unroll
        for (int n = 0; n < 16; ++n) acc[n] = cb;
        for (int k = 0; k < 100; ++k) {
            float a = A[(size_t)k * 600 + c];
            #pragma unroll
            for (int n = 0; n < 16; ++n) acc[n] = fmaf(Ds[n][k], a, acc[n]);
        }
        #pragma unroll
        for (int n = 0; n < 16; ++n) QW[(size_t)(n0 + n) * 600 + c] = acc[n];
    }
}

// ---------- edge kernel: LDS-free, G=2 (32 edges/wave) under the proven 128-reg cap ----------
// Two independent edge chains per wave (ILP to hide VMEM latency); Wvp L2 traffic halved.
// Round-5 structure (functionally verified); the (256,3)=85-reg cap was the sole failure cause.
__global__ __launch_bounds__(256, 2) void k_edge(
        const float* __restrict__ src_h, const float* __restrict__ efeat,
        const float* __restrict__ td,    const int* __restrict__ edge_dst,
        const float* __restrict__ time_w, const float* __restrict__ time_b,
        const unsigned short* __restrict__ Wvp, const float* __restrict__ wkv_b,
        const float* __restrict__ QW,
        unsigned short* __restrict__ Vb, float2* __restrict__ attn) {
    const int t = threadIdx.x, lane = t & 63;
    const int g0 = blockIdx.x * 8 + (t >> 6) * 2;      // this wave: groups g0, g0+1
    const int col = lane & 15, slice = lane >> 4;
    const int r0 = g0 * 16 + col, r1 = r0 + 16;
    const int d0 = edge_dst[r0], d1 = edge_dst[r1];
    const float td0 = td[r0], td1 = td[r1];
    const float* __restrict__ qw0 = QW + (size_t)d0 * 600;
    const float* __restrict__ qw1 = QW + (size_t)d1 * 600;
    const short8b* __restrict__ Wv8 = (const short8b*)Wvp;

    f32x4 acc0[7], acc1[7];
    #pragma unroll
    for (int n = 0; n < 7; ++n) {
        int cl = n * 16 + col;
        float b = (cl < 100) ? wkv_b[100 + cl] : 0.f;
        acc0[n] = (f32x4){b, b, b, b};
        acc1[n] = (f32x4){b, b, b, b};
    }
    float p00 = 0.f, p01 = 0.f, p10 = 0.f, p11 = 0.f;

    #pragma unroll
    for (int kc = 0; kc < 12; ++kc) {
        const int idx0 = (kc & 3) * 32 + slice * 8;    // idx within region: 0..120
        const bool full = (idx0 <= 88);                // 8 valid elems
        const bool part = (idx0 == 96);                // 4 valid elems (96..99)
        float4 z4 = make_float4(0.f, 0.f, 0.f, 0.f);
        float4 xa0 = z4, xb0 = z4, xa1 = z4, xb1 = z4;
        if (kc < 8) {                                  // src (kc<4) / efeat (kc<8)
            const float* __restrict__ base = (kc < 4) ? src_h : efeat;
            const float* b0 = base + (size_t)r0 * 100 + idx0;
            const float* b1 = base + (size_t)r1 * 100 + idx0;
            if (full) {
                xa0 = *(const float4*)b0; xb0 = *(const float4*)(b0 + 4);
                xa1 = *(const float4*)b1; xb1 = *(const float4*)(b1 + 4);
            } else if (part) {
                xa0 = *(const float4*)b0; xa1 = *(const float4*)b1;
            }
        } else {                                       // time features
            if (full || part) {
                float4 tw = *(const float4*)(time_w + idx0);
                float4 tb = *(const float4*)(time_b + idx0);
                xa0.x = __cosf(fmaf(td0, tw.x, tb.x)); xa0.y = __cosf(fmaf(td0, tw.y, tb.y));
                xa0.z = __cosf(fmaf(td0, tw.z, tb.z)); xa0.w = __cosf(fmaf(td0, tw.w, tb.w));
                xa1.x = __cosf(fmaf(td1, tw.x, tb.x)); xa1.y = __cosf(fmaf(td1, tw.y, tb.y));
                xa1.z = __cosf(fmaf(td1, tw.z, tb.z)); xa1.w = __cosf(fmaf(td1, tw.w, tb.w));
                if (full) {
                    float4 tw2 = *(const float4*)(time_w + idx0 + 4);
                    float4 tb2 = *(const float4*)(time_b + idx0 + 4);
                    xb0.x = __cosf(fmaf(td0, tw2.x, tb2.x)); xb0.y = __cosf(fmaf(td0, tw2.y, tb2.y));
                    xb0.z = __cosf(fmaf(td0, tw2.z, tb2.z)); xb0.w = __cosf(fmaf(td0, tw2.w, tb2.w));
                    xb1.x = __cosf(fmaf(td1, tw2.x, tb2.x)); xb1.y = __cosf(fmaf(td1, tw2.y, tb2.y));
                    xb1.z = __cosf(fmaf(td1, tw2.z, tb2.z)); xb1.w = __cosf(fmaf(td1, tw2.w, tb2.w));
                }
            }
        }
        // fused fp32 logits: p += x . QW[dst] over this lane's k-slice
        if (full || part) {
            const int kb = (kc >> 2) * 100 + idx0;
            p00 = dot4(xa0, *(const float4*)(qw0 + kb),       p00);
            p01 = dot4(xa0, *(const float4*)(qw0 + 300 + kb), p01);
            p10 = dot4(xa1, *(const float4*)(qw1 + kb),       p10);
            p11 = dot4(xa1, *(const float4*)(qw1 + 300 + kb), p11);
            if (full) {
                p00 = dot4(xb0, *(const float4*)(qw0 + kb + 4),   p00);
                p01 = dot4(xb0, *(const float4*)(qw0 + 304 + kb), p01);
                p10 = dot4(xb1, *(const float4*)(qw1 + kb + 4),   p10);
                p11 = dot4(xb1, *(const float4*)(qw1 + 304 + kb), p11);
            }
        }
        // pack A fragments (bf16)
        short8b a0, a1;
        a0[0] = (short)f2bf(xa0.x); a0[1] = (short)f2bf(xa0.y);
        a0[2] = (short)f2bf(xa0.z); a0[3] = (short)f2bf(xa0.w);
        a0[4] = (short)f2bf(xb0.x); a0[5] = (short)f2bf(xb0.y);
        a0[6] = (short)f2bf(xb0.z); a0[7] = (short)f2bf(xb0.w);
        a1[0] = (short)f2bf(xa1.x); a1[1] = (short)f2bf(xa1.y);
        a1[2] = (short)f2bf(xa1.z); a1[3] = (short)f2bf(xa1.w);
        a1[4] = (short)f2bf(xb1.x); a1[5] = (short)f2bf(xb1.y);
        a1[6] = (short)f2bf(xb1.z); a1[7] = (short)f2bf(xb1.w);
        // B frags + MFMA (w transient: 1 frag live at a time, reused for both chains)
        #pragma unroll
        for (int n = 0; n < 7; ++n) {
            short8b w = Wv8[(kc * 7 + n) * 64 + lane];
            acc0[n] = __builtin_amdgcn_mfma_f32_16x16x32_bf16(a0, w, acc0[n], 0, 0, 0);
            acc1[n] = __builtin_amdgcn_mfma_f32_16x16x32_bf16(a1, w, acc1[n], 0, 0, 0);
        }
    }
    // logit slice-reduce across the 4 k-slices, leaky, write
    p00 += __shfl_xor(p00, 16); p00 += __shfl_xor(p00, 32);
    p01 += __shfl_xor(p01, 16); p01 += __shfl_xor(p01, 32);
    p10 += __shfl_xor(p10, 16); p10 += __shfl_xor(p10, 32);
    p11 += __shfl_xor(p11, 16); p11 += __shfl_xor(p11, 32);
    if (slice == 0) {
        attn[r0] = make_float2(p00 > 0.f ? p00 : 0.2f * p00,
                               p01 > 0.f ? p01 : 0.2f * p01);
        attn[r1] = make_float2(p10 > 0.f ? p10 : 0.2f * p10,
                               p11 > 0.f ? p11 : 0.2f * p11);
    }
    // V writeout (bf16): C/D layout col=lane&15, row=(lane>>4)*4+r  [m89-verified]
    const int re0 = g0 * 16 + (slice << 2);
    #pragma unroll
    for (int n = 0; n < 7; ++n) {
        int cl = n * 16 + col;
        if (cl < 100) {
            #pragma unroll
            for (int r = 0; r < 4; ++r) {
                Vb[(size_t)(re0 + r) * 100 + cl]      = f2bf(acc0[n][r]);
                Vb[(size_t)(re0 + 16 + r) * 100 + cl] = f2bf(acc1[n][r]);
            }
        }
    }
}

// ---------- segment softmax + weighted V reduce: one wave/node, 4-way unrolled chain ----------
__global__ __launch_bounds__(256) void k_soft(const float2* __restrict__ attn,
                                              const unsigned short* __restrict__ V,
                                              const int* __restrict__ off,
                                              float* __restrict__ agg) {
    const int lane = threadIdx.x & 63;
    const int n = blockIdx.x * 4 + (threadIdx.x >> 6);
    const int r0 = off[n], cnt = off[n + 1] - r0;
    float* __restrict__ aout = agg + (size_t)n * 100;
    if (cnt <= 0) {
        aout[lane] = 0.f;
        if (lane < 36) aout[64 + lane] = 0.f;
        return;
    }
    float m0 = -1e30f, m1 = -1e30f;
    for (int i = lane; i < cnt; i += 64) {
        float2 a = attn[r0 + i];
        m0 = fmaxf(m0, a.x); m1 = fmaxf(m1, a.y);
    }
    #pragma unroll
    for (int s = 1; s < 64; s <<= 1) {
        m0 = fmaxf(m0, __shfl_xor(m0, s));
        m1 = fmaxf(m1, __shfl_xor(m1, s));
    }
    float s0 = 0.f, s1 = 0.f;
    for (int i = lane; i < cnt; i += 64) {
        float2 a = attn[r0 + i];
        s0 += __expf(a.x - m0); s1 += __expf(a.y - m1);
    }
    #pragma unroll
    for (int s = 1; s < 64; s <<= 1) { s0 += __shfl_xor(s0, s); s1 += __shfl_xor(s1, s); }
    const float inv0 = 1.f / s0, inv1 = 1.f / s1;

    float aa0 = 0.f, aa1 = 0.f, aa2 = 0.f, aa3 = 0.f;
    float ab0 = 0.f, ab1 = 0.f, ab2 = 0.f, ab3 = 0.f;
    for (int base = 0; base < cnt; base += 64) {
        int i = base + lane;
        float e0 = 0.f, e1 = 0.f;
        if (i < cnt) {
            float2 a = attn[r0 + i];
            e0 = __expf(a.x - m0) * inv0;
            e1 = __expf(a.y - m1) * inv1;
        }
        int lim = min(64, cnt - base);
        const unsigned short* __restrict__ vrow = V + (size_t)(r0 + base) * 100;
        int j = 0;
        for (; j + 4 <= lim; j += 4) {
            float q00 = __shfl(e0, j),     q10 = __shfl(e1, j);
            float q01 = __shfl(e0, j + 1), q11 = __shfl(e1, j + 1);
            float q02 = __shfl(e0, j + 2), q12 = __shfl(e1, j + 2);
            float q03 = __shfl(e0, j + 3), q13 = __shfl(e1, j + 3);
            const unsigned short* w0 = vrow + (size_t)j * 100;
            float pa0 = (lane < 50) ? q00 : q10;
            float pa1 = (lane < 50) ? q01 : q11;
            float pa2 = (lane < 50) ? q02 : q12;
            float pa3 = (lane < 50) ? q03 : q13;
            aa0 = fmaf(pa0, bf2f(w0[lane]),       aa0);
            aa1 = fmaf(pa1, bf2f(w0[100 + lane]), aa1);
            aa2 = fmaf(pa2, bf2f(w0[200 + lane]), aa2);
            aa3 = fmaf(pa3, bf2f(w0[300 + lane]), aa3);
            if (lane < 36) {
                ab0 = fmaf(q10, bf2f(w0[64 + lane]),  ab0);
                ab1 = fmaf(q11, bf2f(w0[164 + lane]), ab1);
                ab2 = fmaf(q12, bf2f(w0[264 + lane]), ab2);
                ab3 = fmaf(q13, bf2f(w0[364 + lane]), ab3);
            }
        }
        for (; j < lim; ++j) {
            float q0 = __shfl(e0, j), q1 = __shfl(e1, j);
            const unsigned short* w0 = vrow + (size_t)j * 100;
            float pa = (lane < 50) ? q0 : q1;
            aa0 = fmaf(pa, bf2f(w0[lane]), aa0);
            if (lane < 36) ab0 = fmaf(q1, bf2f(w0[64 + lane]), ab0);
        }
    }
    aout[lane] = (aa0 + aa1) + (aa2 + aa3);
    if (lane < 36) aout[64 + lane] = (ab0 + ab1) + (ab2 + ab3);
}

// ---------- out proj + relu + layernorm: 8 nodes/block, coalesced wout_t ----------
__global__ __launch_bounds__(128) void k_out(const float* __restrict__ agg,
                                             const float* __restrict__ dst_h,
                                             const float* __restrict__ wout_t,
                                             const float* __restrict__ wout_b,
                                             const float* __restrict__ ln_g,
                                             const float* __restrict__ ln_b,
                                             float* __restrict__ out) {
    __shared__ float Fs[8][200];
    __shared__ float red[8][128];
    const int n0 = blockIdx.x * 8, t = threadIdx.x;
    for (int idx = t; idx < 1600; idx += 128) {
        int n = idx / 200, i = idx % 200;
        Fs[n][i] = (i < 100) ? agg[(size_t)(n0 + n) * 100 + i]
                             : dst_h[(size_t)(n0 + n) * 100 + (i - 100)];
    }
    __syncthreads();
    float v[8] = {0.f, 0.f, 0.f, 0.f, 0.f, 0.f, 0.f, 0.f};
    if (t < 100) {
        float b = wout_b[t];
        #pragma unroll
        for (int n = 0; n < 8; ++n) v[n] = b;
        for (int i = 0; i < 200; ++i) {
            float w = wout_t[i * 100 + t];        // lanes contiguous -> coalesced
            #pragma unroll
            for (int n = 0; n < 8; ++n) v[n] = fmaf(Fs[n][i], w, v[n]);
        }
        #pragma unroll
        for (int n = 0; n < 8; ++n) v[n] = fmaxf(v[n], 0.f);
    }
    #pragma unroll
    for (int n = 0; n < 8; ++n) red[n][t] = (t < 100) ? v[n] : 0.f;
    __syncthreads();
    for (int s = 64; s > 0; s >>= 1) {
        if (t < s) {
            #pragma unroll
            for (int n = 0; n < 8; ++n) red[n][t] += red[n][t + s];
        }
        __syncthreads();
    }
    float mu[8];
    #pragma unroll
    for (int n = 0; n < 8; ++n) mu[n] = red[n][0] * 0.01f;
    __syncthreads();
    #pragma unroll
    for (int n = 0; n < 8; ++n) {
        float dv = (t < 100) ? (v[n] - mu[n]) : 0.f;
        red[n][t] = dv * dv;
    }
    __syncthreads();
    for (int s = 64; s > 0; s >>= 1) {
        if (t < s) {
            #pragma unroll
            for (int n = 0; n < 8; ++n) red[n][t] += red[n][t + s];
        }
        __syncthreads();
    }
    if (t < 100) {
        #pragma unroll
        for (int n = 0; n < 8; ++n) {
            float var = red[n][0] * 0.01f;
            out[(size_t)(n0 + n) * 100 + t] =
                (v[n] - mu[n]) * rsqrtf(var + LN_EPS) * ln_g[t] + ln_b[t];
        }
    }
}

extern "C" void kernel_launch(void* const* d_in, const int* in_sizes, int n_in,
                              void* d_out, int out_size, void* d_ws, size_t ws_size,
                              hipStream_t stream) {
    const float* dst_h   = (const float*)d_in[0];
    const float* src_h   = (const float*)d_in[1];
    const float* efeat   = (const float*)d_in[2];
    const float* td      = (const float*)d_in[3];
    const int*   edst    = (const int*)  d_in[4];
    const float* time_w  = (const float*)d_in[5];
    const float* time_b  = (const float*)d_in[6];
    const float* wq_w    = (const float*)d_in[7];
    const float* wq_b    = (const float*)d_in[8];
    const float* wkv_w   = (const float*)d_in[9];
    const float* wkv_b   = (const float*)d_in[10];
    const float* wout_w  = (const float*)d_in[11];
    const float* wout_b  = (const float*)d_in[12];
    const float* ln_g    = (const float*)d_in[13];
    const float* ln_b    = (const float*)d_in[14];
    float* out = (float*)d_out;

    char* ws = (char*)d_ws;
    size_t off = 0;
    auto carve = [&](size_t bytes) { char* p = ws + off; off = (off + bytes + 255) & ~(size_t)255; return p; };
    float*          QW    = (float*)carve((size_t)N_DST * 600 * 4);
    float2*         attn  = (float2*)carve((size_t)N_EDGE * 2 * 4);
    unsigned short* Vb    = (unsigned short*)carve((size_t)N_EDGE * 100 * 2);
    float*          agg   = (float*)carve((size_t)N_DST * 100 * 4);
    unsigned short* Wvp   = (unsigned short*)carve(43008 * 2);
    float*          zq    = (float*)carve(100 * 4);
    float*          A     = (float*)carve(60000 * 4);
    float*          C     = (float*)carve(600 * 4);
    float*          woutT = (float*)carve(20000 * 4);
    int*            offs  = (int*)carve((size_t)(N_DST + 1) * 4);

    k_prep<<<(63108 + 255) / 256, 256, 0, stream>>>(wkv_w, wq_w, wq_b, time_b, wout_w,
                                                    Wvp, zq, woutT);
    k_precomp<<<(60600 + 255) / 256, 256, 0, stream>>>(wq_w, wkv_w, zq, A, C);
    k_offsets<<<(N_DST + 1 + 255) / 256, 256, 0, stream>>>(edst, offs);
    k_qw<<<N_DST / 16, 256, 0, stream>>>(dst_h, A, C, QW);
    k_edge<<<N_EDGE / 128, 256, 0, stream>>>(src_h, efeat, td, edst, time_w, time_b,
                                             Wvp, wkv_b, QW, Vb, attn);
    k_soft<<<N_DST / 4, 256, 0, stream>>>(attn, Vb, offs, agg);
    k_out<<<N_DST / 8, 128, 0, stream>>>(agg, dst_h, woutT, wout_b, ln_g, ln_b, out);
}